// Round 2
// baseline (302.663 us; speedup 1.0000x reference)
//
#include <hip/hip_runtime.h>
#include <hip/hip_fp16.h>

// NNConv on MI355X. msg[E x 32] = Z[E x 4096] @ w2r[4096 x 32],
// Z[e, c*32+i] = h[e,c]*xs[e,i] built on the fly in fp16 A-fragments via
// v_pk_mul_f16.
// Round 12: 4 edge-groups per wave (128 edges/wave, 2-wave blocks).
// Each w2 B-column (loaded once per wave from L2) now feeds 8 MFMAs
// (4 accumulators) instead of 4 -- per-wave MFMA supply doubles at the
// same load-stall cost, and w2 L2 traffic halves to 800 MB. Barrier-free:
// B-columns stream through a 2-deep register double buffer (16 VGPRs,
// prefetch distance = 1 column-compute ~ 256 pipe-cycles > 200cy L2 lat).
// hTq is full 32-row wave-private LDS (16 KB/block), no held/flush.
// 1563 blocks vs 1536 concurrent (6/CU) -> 1.7% tail.

#define NN 25000
#define EE 400000

typedef _Float16 f16x8 __attribute__((ext_vector_type(8)));
typedef float    f32x16 __attribute__((ext_vector_type(16)));

// ---------------- prep: pack w1/w2/b2 to fp16 fragment layout + zero replicas ----------------
__global__ __launch_bounds__(256) void prep_kernel(
    const float* __restrict__ w1, const float* __restrict__ w2,
    const float* __restrict__ b2,
    _Float16* __restrict__ w2p, _Float16* __restrict__ w1p, _Float16* __restrict__ b2p,
    float4* __restrict__ part4, int nzero4)
{
    int b = blockIdx.x;
    if (b < 532) {                       // 532*256 = 136192 pack threads, exact
        int t = b * 256 + threadIdx.x;
        if (t < 131072) {
            int j = t & 7, lane = (t >> 3) & 63, ih = (t >> 9) & 1, c = t >> 10;
            w2p[t] = (_Float16)w2[c * 1024 + (ih * 16 + ((lane >> 5) << 3) + j) * 32 + (lane & 31)];
        } else if (t < 135168) {
            int u = t - 131072;
            int j = u & 7, lane = (u >> 3) & 63, kk = (u >> 9) & 1, r = u >> 10;
            w1p[u] = (_Float16)w1[(kk * 16 + ((lane >> 5) << 3) + j) * 128 + r * 32 + (lane & 31)];
        } else {
            int u = t - 135168;
            int j = u & 7, lane = (u >> 3) & 63, ih = u >> 9;
            b2p[u] = (_Float16)b2[(ih * 16 + ((lane >> 5) << 3) + j) * 32 + (lane & 31)];
        }
    } else {
        int z = (b - 532) * 256 + threadIdx.x;
        if (z < nzero4) part4[z] = make_float4(0.f, 0.f, 0.f, 0.f);
    }
}

// ---------------- final: out = x@root + bias + sum(replicas) ----------------
__global__ __launch_bounds__(256) void final_kernel(
    const float* __restrict__ x, const float* __restrict__ root,
    const float* __restrict__ bias, const float* __restrict__ part,
    int ncopies, float* __restrict__ out)
{
    int gid = blockIdx.x * 256 + threadIdx.x;   // exactly NN*32
    int n = gid >> 5, o = gid & 31;
    float acc = bias[o];
    const float* xr = x + (n << 5);
#pragma unroll
    for (int i = 0; i < 32; ++i)
        acc = fmaf(xr[i], root[(i << 5) + o], acc);
    for (int c = 0; c < ncopies; ++c) acc += part[(size_t)c * 800000 + gid];
    out[gid] = acc;
}

// ---------------- fused MFMA edge kernel (barrier-free, 4 groups/wave) ----------------
// 128 thr = 2 waves x 128 edges (4 groups of 32) = 256 edges/block, 1563 blocks.
__global__ __launch_bounds__(128, 3) void edge_kernel(
    const float*    __restrict__ x,
    const int*      __restrict__ ei,
    const float*    __restrict__ ea,
    const float*    __restrict__ b1,
    const _Float16* __restrict__ w2p,
    const _Float16* __restrict__ w1p,
    const _Float16* __restrict__ b2p,
    float* __restrict__ outp, int copyMask)
{
    __shared__ unsigned short hTq[2][32][32][4];   // 16 KB: [wave][c_in_slice][l][g]

    const int t    = threadIdx.x;
    const int w    = t >> 6;
    const int lane = t & 63;
    const int l    = lane & 31;
    const int half = lane >> 5;

    const int  ebraw = blockIdx.x * 256 + w * 128;
    const bool live  = (ebraw + 128) <= EE;        // wave-uniform; 128 | EE
    const int  ebw   = live ? ebraw : (EE - 128);

    float* __restrict__ myout = outp + (size_t)(blockIdx.x & copyMask) * 800000;

    union u8h { f16x8 v; __half2 h2[4]; };

    // ---- w2 B-columns read DIRECTLY from global (L2-resident, 256 KB) ----
    // column j (global c 0..127): 2 fragments (ih) at f16x8 elem (j*2 + ih)*64 + lane.
    const f16x8* __restrict__ w2f = (const f16x8*)w2p;

    f16x8 BA[2], BB[2];                            // double-buffered columns
    auto loadCol = [&](int j, f16x8 (&B)[2]) {
        const f16x8* p = w2f + (size_t)j * 128 + lane;
        B[0] = p[0];
        B[1] = p[64];
    };
    loadCol(0, BA);                    // get loads flying before reg setup
    loadCol(1, BB);

    // ---- gather xs rows (fp16 pairs) for 4 groups: 32 VGPRs ----
    __half2 xs[4][8];
#pragma unroll
    for (int g = 0; g < 4; ++g) {
        int s = ei[ebw + g * 32 + l];
#pragma unroll
        for (int ih = 0; ih < 2; ++ih) {
            float4 a0 = *(const float4*)(x + s * 32 + ih * 16 + half * 8);
            float4 a1 = *(const float4*)(x + s * 32 + ih * 16 + half * 8 + 4);
            xs[g][ih*4+0] = __float22half2_rn(make_float2(a0.x, a0.y));
            xs[g][ih*4+1] = __float22half2_rn(make_float2(a0.z, a0.w));
            xs[g][ih*4+2] = __float22half2_rn(make_float2(a1.x, a1.y));
            xs[g][ih*4+3] = __float22half2_rn(make_float2(a1.z, a1.w));
        }
    }

    f32x16 acc[4];
#pragma unroll
    for (int g = 0; g < 4; ++g)
#pragma unroll
        for (int i = 0; i < 16; ++i) acc[g][i] = 0.f;

    // ---- phase-1 slice for r: all 32 rows of hT for 4 groups into LDS ----
    // ea re-read per r (4x total): stays L2/L3-hot, trades 16 persistent
    // VGPRs for ~0.2 GB cached traffic.
    auto phase1 = [&](int r) {
        f16x8 w1f0 = *(const f16x8*)(w1p + ((r * 2 + 0) * 64 + lane) * 8);
        f16x8 w1f1 = *(const f16x8*)(w1p + ((r * 2 + 1) * 64 + lane) * 8);
#pragma unroll
        for (int g = 0; g < 4; ++g) {
            const float* p = ea + (size_t)(ebw + g * 32 + l) * 32 + half * 8;
            u8h e0, e1;
            {
                float4 a0 = *(const float4*)(p);
                float4 a1 = *(const float4*)(p + 4);
                e0.h2[0] = __float22half2_rn(make_float2(a0.x, a0.y));
                e0.h2[1] = __float22half2_rn(make_float2(a0.z, a0.w));
                e0.h2[2] = __float22half2_rn(make_float2(a1.x, a1.y));
                e0.h2[3] = __float22half2_rn(make_float2(a1.z, a1.w));
                float4 c0 = *(const float4*)(p + 16);
                float4 c1 = *(const float4*)(p + 20);
                e1.h2[0] = __float22half2_rn(make_float2(c0.x, c0.y));
                e1.h2[1] = __float22half2_rn(make_float2(c0.z, c0.w));
                e1.h2[2] = __float22half2_rn(make_float2(c1.x, c1.y));
                e1.h2[3] = __float22half2_rn(make_float2(c1.z, c1.w));
            }
            f32x16 h;
#pragma unroll
            for (int i = 0; i < 16; ++i) h[i] = 0.f;
            h = __builtin_amdgcn_mfma_f32_32x32x16_f16(w1f0, e0.v, h, 0, 0, 0);
            h = __builtin_amdgcn_mfma_f32_32x32x16_f16(w1f1, e1.v, h, 0, 0, 0);
#pragma unroll
            for (int i = 0; i < 16; ++i) {
                int row = (i & 3) + ((i >> 2) << 3) + (half << 2);   // verified C/D map
                float hv = fmaxf(h[i] + b1[r * 32 + row], 0.f);
                hTq[w][row][l][g] = __half_as_ushort(__float2half(hv));
            }
        }
    };

    // compute one c-column (8 MFMAs: 2 ih x 4 g) from register fragments
    auto computeCol = [&](int cs, const f16x8 (&B)[2]) {
        uint2 u = *(const uint2*)&hTq[w][cs][l][0];
        __half2 ha = *reinterpret_cast<const __half2*>(&u.x);
        __half2 hb = *reinterpret_cast<const __half2*>(&u.y);
        __half2 d[4];
        d[0] = __half2half2(__low2half(ha));
        d[1] = __half2half2(__high2half(ha));
        d[2] = __half2half2(__low2half(hb));
        d[3] = __half2half2(__high2half(hb));
#pragma unroll
        for (int ih = 0; ih < 2; ++ih) {
            f16x8 bfr = B[ih];
#pragma unroll
            for (int g = 0; g < 4; ++g) {
                u8h A;
#pragma unroll
                for (int p = 0; p < 4; ++p)
                    A.h2[p] = __hmul2(d[g], xs[g][ih * 4 + p]);   // v_pk_mul_f16
                acc[g] = __builtin_amdgcn_mfma_f32_32x32x16_f16(A.v, bfr, acc[g], 0, 0, 0);
            }
        }
    };

    // ---- pipeline: no barriers; 2-col prefetch distance. Cols 128/129
    // overread into w1p region (valid workspace, values unused). ----
#pragma unroll 1
    for (int r = 0; r < 4; ++r) {
        phase1(r);                     // wave-private hTq: no barrier needed
#pragma unroll 1
        for (int q = 0; q < 8; ++q) {
            const int j = r * 32 + q * 4;
            computeCol(q * 4 + 0, BA); loadCol(j + 2, BA);
            computeCol(q * 4 + 1, BB); loadCol(j + 3, BB);
            computeCol(q * 4 + 2, BA); loadCol(j + 4, BA);
            computeCol(q * 4 + 3, BB); loadCol(j + 5, BB);
        }
    }

    // ---- b2 contribution: extra K-step with h == 1 (A-fragment = xs, no VALU) ----
#pragma unroll
    for (int ih = 0; ih < 2; ++ih) {
        f16x8 bfr = *(const f16x8*)(b2p + (ih * 64 + lane) * 8);
#pragma unroll
        for (int g = 0; g < 4; ++g) {
            u8h A;
#pragma unroll
            for (int p = 0; p < 4; ++p) A.h2[p] = xs[g][ih * 4 + p];
            acc[g] = __builtin_amdgcn_mfma_f32_32x32x16_f16(A.v, bfr, acc[g], 0, 0, 0);
        }
    }

    // ---- scatter into this block's replica (skip for clamped tail waves) ----
    if (live) {
#pragma unroll
        for (int g = 0; g < 4; ++g)
#pragma unroll
            for (int i = 0; i < 16; ++i) {
                int el = (i & 3) + ((i >> 2) << 3) + (half << 2);
                atomicAdd(myout + ei[EE + ebw + g * 32 + el] * 32 + l, acc[g][i]);
            }
    }
}

extern "C" void kernel_launch(void* const* d_in, const int* in_sizes, int n_in,
                              void* d_out, int out_size, void* d_ws, size_t ws_size,
                              hipStream_t stream) {
    const float* x    = (const float*)d_in[0];
    const int*   ei   = (const int*)  d_in[1];
    const float* ea   = (const float*)d_in[2];
    const float* w1   = (const float*)d_in[3];
    const float* b1   = (const float*)d_in[4];
    const float* w2   = (const float*)d_in[5];
    const float* b2   = (const float*)d_in[6];
    const float* root = (const float*)d_in[7];
    const float* bias = (const float*)d_in[8];
    float* out = (float*)d_out;

    _Float16* w2p = (_Float16*)d_ws;                      // 262144 B
    _Float16* w1p = (_Float16*)((char*)d_ws + 262144);    //   8192 B
    _Float16* b2p = (_Float16*)((char*)d_ws + 270336);    //   2048 B
    const size_t partOff = 272384;
    const size_t one = 800000ull * sizeof(float);         // 3.2 MB per replica
    size_t avail = (ws_size > partOff) ? ws_size - partOff : 0;
    int nc = 0;
    for (int c = 8; c >= 1; c >>= 1)
        if ((size_t)c * one <= avail) { nc = c; break; }

    float* part = (float*)((char*)d_ws + partOff);
    if (nc > 0) {
        int nzero4 = nc * 200000;                         // float4 count
        int zb = (nzero4 + 255) / 256;
        prep_kernel<<<532 + zb, 256, 0, stream>>>(w1, w2, b2, w2p, w1p, b2p,
                                                  (float4*)part, nzero4);
        edge_kernel<<<(EE + 255) / 256, 128, 0, stream>>>(x, ei, ea, b1, w2p, w1p, b2p,
                                                          part, nc - 1);
        final_kernel<<<(NN * 32) / 256, 256, 0, stream>>>(x, root, bias, part, nc, out);
    } else {
        prep_kernel<<<532, 256, 0, stream>>>(w1, w2, b2, w2p, w1p, b2p, (float4*)part, 0);
        final_kernel<<<(NN * 32) / 256, 256, 0, stream>>>(x, root, bias, part, 0, out);
        edge_kernel<<<(EE + 255) / 256, 128, 0, stream>>>(x, ei, ea, b1, w2p, w1p, b2p,
                                                          out, 0);
    }
}

// Round 3
// 235.728 us; speedup vs baseline: 1.2839x; 1.2839x over previous
//
#include <hip/hip_runtime.h>
#include <hip/hip_fp16.h>

// NNConv on MI355X. msg[E x 32] = Z[E x 4096] @ w2r[4096 x 32],
// Z[e, c*32+i] = h[e,c]*xs[e,i] built on the fly in fp16 A-fragments via
// v_pk_mul_f16.
// Round 13: R12's 4-group geometry (128 edges/wave, 8 MFMAs per B-column,
// 800 MB w2 L2 traffic) with the spill fixed:
//  - __launch_bounds__(128,2): 256-VGPR cap (R12's (128,3)=170 cap spilled:
//    WRITE_SIZE 50->264 MB was scratch traffic).
//  - persistent eaf[4][2] (ea read ONCE; R12's re-read-per-r added ~150 MB
//    HBM fetch -- per-XCD L2 is too small to hold 6 blocks' slices).
//  - 4-deep B-column register buffer: prefetch distance 3 columns (~768
//    pipe-cycles) > loaded-L2 latency; R12's rotation was only 1 column.
// Barrier-free; hTq wave-private LDS 16 KB/block.

#define NN 25000
#define EE 400000

typedef _Float16 f16x8 __attribute__((ext_vector_type(8)));
typedef float    f32x16 __attribute__((ext_vector_type(16)));

// ---------------- prep: pack w1/w2/b2 to fp16 fragment layout + zero replicas ----------------
__global__ __launch_bounds__(256) void prep_kernel(
    const float* __restrict__ w1, const float* __restrict__ w2,
    const float* __restrict__ b2,
    _Float16* __restrict__ w2p, _Float16* __restrict__ w1p, _Float16* __restrict__ b2p,
    float4* __restrict__ part4, int nzero4)
{
    int b = blockIdx.x;
    if (b < 532) {                       // 532*256 = 136192 pack threads, exact
        int t = b * 256 + threadIdx.x;
        if (t < 131072) {
            int j = t & 7, lane = (t >> 3) & 63, ih = (t >> 9) & 1, c = t >> 10;
            w2p[t] = (_Float16)w2[c * 1024 + (ih * 16 + ((lane >> 5) << 3) + j) * 32 + (lane & 31)];
        } else if (t < 135168) {
            int u = t - 131072;
            int j = u & 7, lane = (u >> 3) & 63, kk = (u >> 9) & 1, r = u >> 10;
            w1p[u] = (_Float16)w1[(kk * 16 + ((lane >> 5) << 3) + j) * 128 + r * 32 + (lane & 31)];
        } else {
            int u = t - 135168;
            int j = u & 7, lane = (u >> 3) & 63, ih = u >> 9;
            b2p[u] = (_Float16)b2[(ih * 16 + ((lane >> 5) << 3) + j) * 32 + (lane & 31)];
        }
    } else {
        int z = (b - 532) * 256 + threadIdx.x;
        if (z < nzero4) part4[z] = make_float4(0.f, 0.f, 0.f, 0.f);
    }
}

// ---------------- final: out = x@root + bias + sum(replicas) ----------------
__global__ __launch_bounds__(256) void final_kernel(
    const float* __restrict__ x, const float* __restrict__ root,
    const float* __restrict__ bias, const float* __restrict__ part,
    int ncopies, float* __restrict__ out)
{
    int gid = blockIdx.x * 256 + threadIdx.x;   // exactly NN*32
    int n = gid >> 5, o = gid & 31;
    float acc = bias[o];
    const float* xr = x + (n << 5);
#pragma unroll
    for (int i = 0; i < 32; ++i)
        acc = fmaf(xr[i], root[(i << 5) + o], acc);
    for (int c = 0; c < ncopies; ++c) acc += part[(size_t)c * 800000 + gid];
    out[gid] = acc;
}

// ---------------- fused MFMA edge kernel (barrier-free, 4 groups/wave) ----------------
// 128 thr = 2 waves x 128 edges (4 groups of 32) = 256 edges/block, 1563 blocks.
__global__ __launch_bounds__(128, 2) void edge_kernel(
    const float*    __restrict__ x,
    const int*      __restrict__ ei,
    const float*    __restrict__ ea,
    const float*    __restrict__ b1,
    const _Float16* __restrict__ w2p,
    const _Float16* __restrict__ w1p,
    const _Float16* __restrict__ b2p,
    float* __restrict__ outp, int copyMask)
{
    __shared__ unsigned short hTq[2][32][32][4];   // 16 KB: [wave][c_in_slice][l][g]

    const int t    = threadIdx.x;
    const int w    = t >> 6;
    const int lane = t & 63;
    const int l    = lane & 31;
    const int half = lane >> 5;

    const int  ebraw = blockIdx.x * 256 + w * 128;
    const bool live  = (ebraw + 128) <= EE;        // wave-uniform; 128 | EE
    const int  ebw   = live ? ebraw : (EE - 128);

    float* __restrict__ myout = outp + (size_t)(blockIdx.x & copyMask) * 800000;

    union u8h { f16x8 v; __half2 h2[4]; };

    // ---- w2 B-columns read DIRECTLY from global (L2-resident, 256 KB) ----
    // column j (global c 0..127): 2 fragments (ih) at f16x8 elem (j*2 + ih)*64 + lane.
    const f16x8* __restrict__ w2f = (const f16x8*)w2p;

    f16x8 BA[2], BB[2], BC[2], BD[2];              // 4-deep column buffers
    auto loadCol = [&](int j, f16x8 (&B)[2]) {
        const f16x8* p = w2f + (size_t)j * 128 + lane;
        B[0] = p[0];
        B[1] = p[64];
    };
    loadCol(0, BA);                    // get loads flying before reg setup
    loadCol(1, BB);
    loadCol(2, BC);
    loadCol(3, BD);

    // ---- persistent edge-attr fragments (fp16), 4 groups; read ONCE (32 VGPR) ----
    u8h eaf[4][2];
#pragma unroll
    for (int g = 0; g < 4; ++g)
#pragma unroll
        for (int kk = 0; kk < 2; ++kk) {
            const float* p = ea + (size_t)(ebw + g * 32 + l) * 32 + kk * 16 + half * 8;
            float4 a0 = *(const float4*)p;
            float4 a1 = *(const float4*)(p + 4);
            eaf[g][kk].h2[0] = __float22half2_rn(make_float2(a0.x, a0.y));
            eaf[g][kk].h2[1] = __float22half2_rn(make_float2(a0.z, a0.w));
            eaf[g][kk].h2[2] = __float22half2_rn(make_float2(a1.x, a1.y));
            eaf[g][kk].h2[3] = __float22half2_rn(make_float2(a1.z, a1.w));
        }

    // ---- gather xs rows (fp16 pairs) for 4 groups: 32 VGPRs ----
    __half2 xs[4][8];
#pragma unroll
    for (int g = 0; g < 4; ++g) {
        int s = ei[ebw + g * 32 + l];
#pragma unroll
        for (int ih = 0; ih < 2; ++ih) {
            float4 a0 = *(const float4*)(x + s * 32 + ih * 16 + half * 8);
            float4 a1 = *(const float4*)(x + s * 32 + ih * 16 + half * 8 + 4);
            xs[g][ih*4+0] = __float22half2_rn(make_float2(a0.x, a0.y));
            xs[g][ih*4+1] = __float22half2_rn(make_float2(a0.z, a0.w));
            xs[g][ih*4+2] = __float22half2_rn(make_float2(a1.x, a1.y));
            xs[g][ih*4+3] = __float22half2_rn(make_float2(a1.z, a1.w));
        }
    }

    f32x16 acc[4];
#pragma unroll
    for (int g = 0; g < 4; ++g)
#pragma unroll
        for (int i = 0; i < 16; ++i) acc[g][i] = 0.f;

    // ---- phase-1 slice for r: all 32 rows of hT for 4 groups into LDS ----
    auto phase1 = [&](int r) {
        f16x8 w1f0 = *(const f16x8*)(w1p + ((r * 2 + 0) * 64 + lane) * 8);
        f16x8 w1f1 = *(const f16x8*)(w1p + ((r * 2 + 1) * 64 + lane) * 8);
#pragma unroll
        for (int g = 0; g < 4; ++g) {
            f32x16 h;
#pragma unroll
            for (int i = 0; i < 16; ++i) h[i] = 0.f;
            h = __builtin_amdgcn_mfma_f32_32x32x16_f16(w1f0, eaf[g][0].v, h, 0, 0, 0);
            h = __builtin_amdgcn_mfma_f32_32x32x16_f16(w1f1, eaf[g][1].v, h, 0, 0, 0);
#pragma unroll
            for (int i = 0; i < 16; ++i) {
                int row = (i & 3) + ((i >> 2) << 3) + (half << 2);   // verified C/D map
                float hv = fmaxf(h[i] + b1[r * 32 + row], 0.f);
                hTq[w][row][l][g] = __half_as_ushort(__float2half(hv));
            }
        }
    };

    // compute one c-column (8 MFMAs: 2 ih x 4 g) from register fragments
    auto computeCol = [&](int cs, const f16x8 (&B)[2]) {
        uint2 u = *(const uint2*)&hTq[w][cs][l][0];
        __half2 ha = *reinterpret_cast<const __half2*>(&u.x);
        __half2 hb = *reinterpret_cast<const __half2*>(&u.y);
        __half2 d[4];
        d[0] = __half2half2(__low2half(ha));
        d[1] = __half2half2(__high2half(ha));
        d[2] = __half2half2(__low2half(hb));
        d[3] = __half2half2(__high2half(hb));
#pragma unroll
        for (int ih = 0; ih < 2; ++ih) {
            f16x8 bfr = B[ih];
#pragma unroll
            for (int g = 0; g < 4; ++g) {
                u8h A;
#pragma unroll
                for (int p = 0; p < 4; ++p)
                    A.h2[p] = __hmul2(d[g], xs[g][ih * 4 + p]);   // v_pk_mul_f16
                acc[g] = __builtin_amdgcn_mfma_f32_32x32x16_f16(A.v, bfr, acc[g], 0, 0, 0);
            }
        }
    };

    // ---- pipeline: no barriers; 3-col prefetch distance via 4 buffers.
    // Max overread: col 131 -> bytes < 269312, lands in w1p/b2p workspace
    // region (valid memory, values unused). ----
#pragma unroll 1
    for (int r = 0; r < 4; ++r) {
        phase1(r);                     // wave-private hTq: no barrier needed
#pragma unroll 1
        for (int q = 0; q < 8; ++q) {
            const int j = r * 32 + q * 4;
            computeCol(q * 4 + 0, BA); loadCol(j + 4, BA);
            computeCol(q * 4 + 1, BB); loadCol(j + 5, BB);
            computeCol(q * 4 + 2, BC); loadCol(j + 6, BC);
            computeCol(q * 4 + 3, BD); loadCol(j + 7, BD);
        }
    }

    // ---- b2 contribution: extra K-step with h == 1 (A-fragment = xs, no VALU) ----
#pragma unroll
    for (int ih = 0; ih < 2; ++ih) {
        f16x8 bfr = *(const f16x8*)(b2p + (ih * 64 + lane) * 8);
#pragma unroll
        for (int g = 0; g < 4; ++g) {
            u8h A;
#pragma unroll
            for (int p = 0; p < 4; ++p) A.h2[p] = xs[g][ih * 4 + p];
            acc[g] = __builtin_amdgcn_mfma_f32_32x32x16_f16(A.v, bfr, acc[g], 0, 0, 0);
        }
    }

    // ---- scatter into this block's replica (skip for clamped tail waves) ----
    if (live) {
#pragma unroll
        for (int g = 0; g < 4; ++g)
#pragma unroll
            for (int i = 0; i < 16; ++i) {
                int el = (i & 3) + ((i >> 2) << 3) + (half << 2);
                atomicAdd(myout + ei[EE + ebw + g * 32 + el] * 32 + l, acc[g][i]);
            }
    }
}

extern "C" void kernel_launch(void* const* d_in, const int* in_sizes, int n_in,
                              void* d_out, int out_size, void* d_ws, size_t ws_size,
                              hipStream_t stream) {
    const float* x    = (const float*)d_in[0];
    const int*   ei   = (const int*)  d_in[1];
    const float* ea   = (const float*)d_in[2];
    const float* w1   = (const float*)d_in[3];
    const float* b1   = (const float*)d_in[4];
    const float* w2   = (const float*)d_in[5];
    const float* b2   = (const float*)d_in[6];
    const float* root = (const float*)d_in[7];
    const float* bias = (const float*)d_in[8];
    float* out = (float*)d_out;

    _Float16* w2p = (_Float16*)d_ws;                      // 262144 B
    _Float16* w1p = (_Float16*)((char*)d_ws + 262144);    //   8192 B
    _Float16* b2p = (_Float16*)((char*)d_ws + 270336);    //   2048 B
    const size_t partOff = 272384;
    const size_t one = 800000ull * sizeof(float);         // 3.2 MB per replica
    size_t avail = (ws_size > partOff) ? ws_size - partOff : 0;
    int nc = 0;
    for (int c = 8; c >= 1; c >>= 1)
        if ((size_t)c * one <= avail) { nc = c; break; }

    float* part = (float*)((char*)d_ws + partOff);
    if (nc > 0) {
        int nzero4 = nc * 200000;                         // float4 count
        int zb = (nzero4 + 255) / 256;
        prep_kernel<<<532 + zb, 256, 0, stream>>>(w1, w2, b2, w2p, w1p, b2p,
                                                  (float4*)part, nzero4);
        edge_kernel<<<(EE + 255) / 256, 128, 0, stream>>>(x, ei, ea, b1, w2p, w1p, b2p,
                                                          part, nc - 1);
        final_kernel<<<(NN * 32) / 256, 256, 0, stream>>>(x, root, bias, part, nc, out);
    } else {
        prep_kernel<<<532, 256, 0, stream>>>(w1, w2, b2, w2p, w1p, b2p, (float4*)part, 0);
        final_kernel<<<(NN * 32) / 256, 256, 0, stream>>>(x, root, bias, part, 0, out);
        edge_kernel<<<(EE + 255) / 256, 128, 0, stream>>>(x, ei, ea, b1, w2p, w1p, b2p,
                                                          out, 0);
    }
}